// Round 6
// baseline (265.065 us; speedup 1.0000x reference)
//
#include <hip/hip_runtime.h>
#include <math.h>

// All inputs/outputs fp32 (verified R2).
// R10: k_sample dedupe 277.2. R11 FAILED (+26, launch overhead). R12 neutral.
// R13: de-serialize (direct L2 weight reads, shfl reductions, ballot ranks) 263.7.
// R14: fuse k_sample INTO k_edge (same grid 384; offsets/logits/ref/lxly stay in
// LDS; gather writes per-head aggregate aggb from registers). Val projection +
// valb moved AFTER 3-point pooling into k_tail (linearity; valwT traffic 100->33MB).
// 3 launches instead of 4.

typedef unsigned int uint;

__device__ __forceinline__ float lo16(uint u) { return __uint_as_float(u << 16); }
__device__ __forceinline__ float hi16(uint u) { return __uint_as_float(u & 0xFFFF0000u); }
__device__ __forceinline__ uint bfr(float x) {  // fp32 -> bf16 bits, RNE
    uint u = __float_as_uint(x);
    return (u + 0x7FFFu + ((u >> 16) & 1u)) >> 16;
}

// shfl-based block sum over threads t<256 (others must pass 0). 2 barriers.
__device__ __forceinline__ float block_sum256f(float v, float* red) {
    int t = threadIdx.x;
    __syncthreads();  // protect red reuse across back-to-back calls
    #pragma unroll
    for (int off = 32; off; off >>= 1) v += __shfl_xor(v, off);
    if (t < 256 && (t & 63) == 0) red[t >> 6] = v;
    __syncthreads();
    return red[0] + red[1] + red[2] + red[3];
}

// ---- tiled GEMM unit (R4-verified): 64 rows x 8 outputs ----
template <int K, int MI, int MO>
__device__ void gemm_unit(const float* __restrict__ IN, const float* __restrict__ IN2,
                          const float* __restrict__ W, const float* __restrict__ B,
                          float* __restrict__ OUT, int O, int OG, int u, float* smem) {
    constexpr int KC = 128;
    constexpr int LDT = KC + 4;
    float* tile = smem;
    int og = u % OG, rg = u / OG;
    int o0 = og * 8, r0 = rg * 64;
    int t = threadIdx.x;
    int r = t & 63;
    int ol = __builtin_amdgcn_readfirstlane(t >> 6);
    int oa = o0 + ol, ob = o0 + 4 + ol;
    const float* Wa = W + (size_t)oa * K;
    const float* Wb = W + (size_t)ob * K;
    float Ba = B[oa], Bb = B[ob];
    float acca = 0.f, accb = 0.f;
    for (int c = 0; c < K / KC; c++) {
        for (int idx = t; idx < 64 * KC; idx += 256) {
            int rr = idx >> 7, ii = idx & (KC - 1);
            int row = r0 + rr, col = c * KC + ii;
            float v;
            if (MI == 0) {
                v = IN[(size_t)row * K + col];
            } else {
                float tv = IN[row * 256 + col];
                v = (o0 < 512) ? tv + IN2[row * 256 + col] : tv;
            }
            tile[rr * LDT + ii] = v;
        }
        __syncthreads();
        const float4* wa4 = (const float4*)(Wa + c * KC);
        const float4* wb4 = (const float4*)(Wb + c * KC);
        const float4* trow = (const float4*)(tile + r * LDT);
        #pragma unroll
        for (int i4 = 0; i4 < KC / 4; i4++) {
            float4 x4 = trow[i4];
            float4 a4 = wa4[i4];
            float4 b4 = wb4[i4];
            acca += x4.x * a4.x; acca += x4.y * a4.y;
            acca += x4.z * a4.z; acca += x4.w * a4.w;
            accb += x4.x * b4.x; accb += x4.y * b4.y;
            accb += x4.z * b4.z; accb += x4.w * b4.w;
        }
        __syncthreads();
    }
    acca += Ba; accb += Bb;
    if (MO == 2) {
        if (oa < 256) acca *= 0.17677669529663687f;
        if (ob < 256) accb *= 0.17677669529663687f;
    }
    OUT[(size_t)(r0 + r) * O + oa] = acca;
    OUT[(size_t)(r0 + r) * O + ob] = accb;
}

// ---- fp32 transpose unit: out[c*256 + r] = in[r][c] (R,C mult of 32) ----
__device__ void transpose_unit(const float* __restrict__ in, float* __restrict__ out,
                               int R, int C, int u, float* smem) {
    int TC = C >> 5;
    int tc = u % TC, tr = u / TC;
    int t = threadIdx.x;
    int lr = t >> 5, lc = t & 31;
    #pragma unroll
    for (int rr = 0; rr < 32; rr += 8)
        smem[(rr + lr) * 33 + lc] = in[(size_t)(tr * 32 + rr + lr) * C + tc * 32 + lc];
    __syncthreads();
    #pragma unroll
    for (int rr = 0; rr < 32; rr += 8)
        out[(size_t)(tc * 32 + rr + lr) * R + tr * 32 + lc] = smem[lc * 33 + rr + lr];
    __syncthreads();
}

// ---- transpose+bf16-pack: P[(k2)*S + F + r] = pack(in[r][2k2], in[r][2k2+1]) ----
__device__ void tpack_unit(const float* __restrict__ in, uint* __restrict__ P,
                           int C, int S, int F, int u, float* smem) {
    int TC = C >> 5;
    int tc = u % TC, tr = u / TC;
    int t = threadIdx.x;
    int lr = t >> 5, lc = t & 31;
    #pragma unroll
    for (int rr = 0; rr < 32; rr += 8)
        smem[(rr + lr) * 33 + lc] = in[(size_t)(tr * 32 + rr + lr) * C + tc * 32 + lc];
    __syncthreads();
    #pragma unroll
    for (int rep = 0; rep < 2; rep++) {
        int idx = rep * 256 + t;
        int c2 = idx >> 5, r = idx & 31;
        uint w0 = bfr(smem[r * 33 + 2 * c2]);
        uint w1 = bfr(smem[r * 33 + 2 * c2 + 1]);
        P[(size_t)(tc * 16 + c2) * S + F + tr * 32 + r] = (w1 << 16) | w0;
    }
    __syncthreads();
}

// ---------------- S1: qkv gemm + weight transposes/packs ----------------
// grid 1152, block 256
__global__ __launch_bounds__(256) void k_prep(const float* __restrict__ tgt,
                                              const float* __restrict__ qpos,
                                              const float* __restrict__ ipw,
                                              const float* __restrict__ ipb,
                                              const float* __restrict__ opw,
                                              const float* __restrict__ ojw,
                                              const float* __restrict__ valw,
                                              const float* __restrict__ l1w,
                                              const float* __restrict__ l2w,
                                              const float* __restrict__ l0w,
                                              const float* __restrict__ offw,
                                              const float* __restrict__ aww,
                                              float* __restrict__ qkv,
                                              float* __restrict__ opwT,
                                              float* __restrict__ ojwT,
                                              float* __restrict__ valwT,
                                              uint* __restrict__ Pl1,
                                              uint* __restrict__ Pl2,
                                              uint* __restrict__ Pl0,
                                              uint* __restrict__ Poaw) {
    __shared__ __align__(16) float smem[8448];
    int u = blockIdx.x;
    if (u < 192)       gemm_unit<256, 1, 2>(tgt, qpos, ipw, ipb, qkv, 768, 96, u, smem);
    else if (u < 256)  transpose_unit(opw, opwT, 256, 256, u - 192, smem);
    else if (u < 320)  transpose_unit(ojw, ojwT, 256, 256, u - 256, smem);
    else if (u < 384)  transpose_unit(valw, valwT, 256, 256, u - 320, smem);
    else if (u < 640)  tpack_unit(l1w, Pl1, 256, 1024, 0, u - 384, smem);
    else if (u < 896)  tpack_unit(l2w, Pl2, 1024, 256, 0, u - 640, smem);
    else if (u < 1056) tpack_unit(l0w, Pl0, 640, 256, 0, u - 896, smem);
    else if (u < 1120) tpack_unit(offw, Poaw, 256, 384, 0, u - 1056, smem);
    else               tpack_unit(aww, Poaw, 256, 384, 256, u - 1120, smem);
}

// ---- geometry for edge e, point j ----
__device__ __forceinline__ void edge_geom(const float* __restrict__ ec, int e, int j,
                                          float* pxs, float* pys,
                                          float& fminx, float& fminy,
                                          float& cxf, float& cyf) {
    float ax = ec[e * 4 + 0], ay = ec[e * 4 + 1];
    float bx = ec[e * 4 + 2], by = ec[e * 4 + 3];
    float dx = bx - ax, dy = by - ay;
    float tj = 0.5f * (float)j;
    float ptx = __fadd_rn(ax, __fmul_rn(tj, dx));
    float pty = __fadd_rn(ay, __fmul_rn(tj, dy));
    cxf = floorf(ptx); cyf = floorf(pty);
    int minx = max((int)cxf - 128, 0); if (minx + 256 > 2048) minx = 2048 - 256;
    int miny = max((int)cyf - 128, 0); if (miny + 256 > 2048) miny = 2048 - 256;
    fminx = (float)minx; fminy = (float)miny;
    float tlx, thx, tly, thy;
    if (dx == 0.f) { tlx = 0.f; thx = 1.f; }
    else { float u1 = (fminx - ax) / dx, u2 = (fminx + 256.f - ax) / dx; tlx = fminf(u1, u2); thx = fmaxf(u1, u2); }
    if (dy == 0.f) { tly = 0.f; thy = 1.f; }
    else { float u1 = (fminy - ay) / dy, u2 = (fminy + 256.f - ay) / dy; tly = fminf(u1, u2); thy = fmaxf(u1, u2); }
    float t0 = fmaxf(fmaxf(tlx, tly), 0.f);
    float t1 = fmaxf(fminf(fminf(thx, thy), 1.f), t0);
    pxs[0] = __fadd_rn(ax, __fmul_rn(t0, dx)); pys[0] = __fadd_rn(ay, __fmul_rn(t0, dy));
    pxs[1] = __fadd_rn(ax, __fmul_rn(t1, dx)); pys[1] = __fadd_rn(ay, __fmul_rn(t1, dy));
    pxs[2] = cxf; pys[2] = cyf;
}

// ---------------- S2: per-POINT fused (grid 384, block 1024) ----------------
// attn(redundant per edge-triple) + oproj + norm2 + pe + nq + offaw + sampling.
// LDS pool (floats):
//  phase A: xq@0(256) sq@256 sS@512(1024) wred@1536(16) ssum@1552(8) srow@1560(256)
//           part@1824(1024) red@2848(8)
//  phase B aliases: pe@256(384) nrow@640(256) partial@896(1024)
//  phase C aliases: offa@0(384) sw@384(512) uw@896(4096) pcs@4992(64)
__global__ __launch_bounds__(1024) void k_edge(const float* __restrict__ qkv,
                                               const float* __restrict__ tgt,
                                               const float* __restrict__ qpos,
                                               const float* __restrict__ opwT,
                                               const float* __restrict__ opb,
                                               const float* __restrict__ n2w,
                                               const float* __restrict__ n2b,
                                               const float* __restrict__ ec,
                                               const uint* __restrict__ Pl0,
                                               const float* __restrict__ l0b,
                                               const uint* __restrict__ Poaw,
                                               const float* __restrict__ offb,
                                               const float* __restrict__ awb,
                                               const float* __restrict__ vr,
                                               const float* __restrict__ src,
                                               const unsigned char* __restrict__ mask,
                                               float* __restrict__ x1,
                                               float* __restrict__ aggb,
                                               float* __restrict__ csumb) {
    int n = blockIdx.x, t = threadIdx.x;
    int e = n / 3, j = n - e * 3;
    __shared__ __align__(16) float SH[5056];
    float* xq   = SH;
    float* sq   = SH + 256;
    float* sS   = SH + 512;
    float* wred = SH + 1536;
    float* ssum = SH + 1552;
    float* srow = SH + 1560;
    float* part = SH + 1824;
    float* red  = SH + 2848;
    float* pe      = SH + 256;   // phase B
    float* nrow    = SH + 640;
    float* partial = SH + 896;
    float* offa = SH;            // phase C
    float* sw   = SH + 384;
    float* uw   = SH + 896;
    float* pcs  = SH + 4992;
    __shared__ int   sg[512], rk[512], ulist[512], wtot[16], slx[8];
    __shared__ float sm[8], sinv[8], sref[2];
    // ---- attention (redundant across the 3 point-blocks of this edge) ----
    if (t < 256) sq[t] = qkv[e * 768 + t];
    __syncthreads();
    int h = t >> 7;
    {
        int f = t & 127;
        const float* kf = qkv + f * 768 + 256 + h * 32;
        const float* qh = sq + h * 32;
        float s = 0.f;
        #pragma unroll 8
        for (int d = 0; d < 32; d++) s += qh[d] * kf[d];
        float m = s;
        #pragma unroll
        for (int off = 32; off; off >>= 1) m = fmaxf(m, __shfl_xor(m, off));
        if ((t & 63) == 0) wred[t >> 6] = m;
        __syncthreads();
        float hm = fmaxf(wred[2 * h], wred[2 * h + 1]);
        float ev = __expf(s - hm);
        sS[t] = ev;
        float su = ev;
        #pragma unroll
        for (int off = 32; off; off >>= 1) su += __shfl_xor(su, off);
        if ((t & 63) == 0) wred[t >> 6] = su;
        __syncthreads();
        if (t < 8) ssum[t] = 1.f / (wred[2 * t] + wred[2 * t + 1]);
    }
    // ---- PV ----
    {
        int o = t & 255, c = t >> 8, hh = o >> 5, d = o & 31;
        float acc = 0.f;
        #pragma unroll 8
        for (int f = c * 32; f < c * 32 + 32; f++)
            acc += sS[hh * 128 + f] * qkv[f * 768 + 512 + hh * 32 + d];
        part[t] = acc;
    }
    __syncthreads();
    if (t < 256) srow[t] = (part[t] + part[256 + t] + part[512 + t] + part[768 + t]) * ssum[t >> 5];
    __syncthreads();
    // ---- oproj ----
    {
        int o = t & 255, c = t >> 8;
        float acc = 0.f;
        #pragma unroll 8
        for (int i = c * 64; i < c * 64 + 64; i++) acc += srow[i] * opwT[(size_t)i * 256 + o];
        part[t] = acc;
    }
    __syncthreads();
    // ---- norm2 -> x1 (j==0 only), xq ----
    {
        float acc = 0.f;
        if (t < 256) acc = part[t] + part[256 + t] + part[512 + t] + part[768 + t] + opb[t] + tgt[e * 256 + t];
        float mean = block_sum256f(acc, red) * (1.f / 256.f);
        float d0 = acc - mean;
        float var = block_sum256f((t < 256) ? d0 * d0 : 0.f, red) * (1.f / 256.f);
        if (t < 256) {
            float xln = d0 * rsqrtf(var + 1e-5f) * n2w[t] + n2b[t];
            if (j == 0) x1[e * 256 + t] = xln;
            xq[t] = xln + qpos[e * 256 + t];
        }
    }
    // ---- pos-encode: own point (384 elems; aliases dead sq/sS) ----
    if (t < 384) {
        float pxs[3], pys[3], fmx, fmy, cxf, cyf;
        edge_geom(ec, e, j, pxs, pys, fmx, fmy, cxf, cyf);
        int jj = t >> 7, tt = t & 127, i = tt & 63, kk = i >> 1;
        float invd = __expf(-(float)kk * (9.210340371976184f / 32.f));  // 10000^(-kk/32)
        float vv = (tt < 64) ? pys[jj] : pxs[jj];
        float pp = vv * invd;
        pe[t] = (i & 1) ? __cosf(pp) : __sinf(pp);
    }
    if (t == 0) {
        float pxs[3], pys[3], fmx, fmy, cxf, cyf;
        edge_geom(ec, e, j, pxs, pys, fmx, fmy, cxf, cyf);
        sref[0] = (cxf - fmx) * (1.f / 256.f);
        sref[1] = (cyf - fmy) * (1.f / 256.f);
        slx[0] = (int)rintf(fmx * 0.125f);
        slx[1] = (int)rintf(fmx * 0.0625f);
        slx[2] = (int)rintf(fmx * 0.03125f);
        slx[3] = (int)rintf(fmx * 0.015625f);
        slx[4] = (int)rintf(fmy * 0.125f);
        slx[5] = (int)rintf(fmy * 0.0625f);
        slx[6] = (int)rintf(fmy * 0.03125f);
        slx[7] = (int)rintf(fmy * 0.015625f);
    }
    __syncthreads();
    // ---- nq: K=640, 256 outs; direct L2 reads ----
    {
        int o = t & 255, kc = t >> 8;
        float acc = 0.f;
        for (int tk = 0; tk < 10; tk++) {
            const float* inb = (tk < 4) ? (xq + tk * 64) : (pe + tk * 64 - 256);
            const uint* P = Pl0 + (size_t)tk * 8192 + (size_t)(kc * 8) * 256 + o;
            #pragma unroll
            for (int kk = 0; kk < 8; kk++) {
                uint u = P[kk * 256];
                acc += inb[(kc * 8 + kk) * 2] * lo16(u);
                acc += inb[(kc * 8 + kk) * 2 + 1] * hi16(u);
            }
        }
        partial[t] = acc;
    }
    __syncthreads();
    if (t < 256) nrow[t] = partial[t] + partial[256 + t] + partial[512 + t] + partial[768 + t] + l0b[t];
    __syncthreads();
    // ---- off+attw: K=256, O=384; direct L2 reads ----
    if (t < 768) {
        int o = t % 384, kc = t / 384;
        float acc = 0.f;
        for (int tk = 0; tk < 4; tk++) {
            const float* inb = nrow + tk * 64 + kc * 32;
            const uint* P = Poaw + (size_t)tk * 12288 + (size_t)(kc * 16) * 384 + o;
            #pragma unroll
            for (int kk = 0; kk < 16; kk++) {
                uint u = P[kk * 384];
                acc += inb[kk * 2] * lo16(u);
                acc += inb[kk * 2 + 1] * hi16(u);
            }
        }
        partial[t] = acc;
    }
    __syncthreads();
    // offsets+logits stay in LDS (offa@0 doesn't overlap partial@896+)
    float offav = 0.f;
    if (t < 384) {
        float b = (t < 256) ? offb[t] : awb[t - 256];
        offav = partial[t] + partial[384 + t] + b;
    }
    __syncthreads();  // partial fully consumed before uw (@896) is zeroed
    if (t < 384) offa[t] = offav;
    #pragma unroll
    for (int z = 0; z < 4; z++) uw[z * 1024 + t] = 0.f;
    __syncthreads();
    // ---- softmax over 16 logits per head ----
    if (t < 8) {
        float m = -1e30f;
        for (int i = 0; i < 16; i++) m = fmaxf(m, offa[256 + t * 16 + i]);
        float s = 0.f;
        for (int i = 0; i < 16; i++) s += __expf(offa[256 + t * 16 + i] - m);
        sm[t] = m; sinv[t] = 1.f / s;
    }
    __syncthreads();
    // ---- all 512 taps (level-major: t = l*128 + h*16 + pp*4 + tap) ----
    if (t < 512) {
        int l = t >> 7, rem = t & 127;
        int hh = rem >> 4, pp = (rem >> 2) & 3, tap = t & 3;
        int s = 32 >> l, wl = 256 >> l;
        const int img_starts[4] = {0, 65536, 81920, 86016};
        float a = __expf(offa[256 + hh * 16 + l * 4 + pp] - sm[hh]) * sinv[hh];
        float slv = (float)s;
        float gx = sref[0] * vr[l * 2 + 0] + offa[hh * 32 + l * 8 + pp * 2 + 0] / slv;
        float gy = sref[1] * vr[l * 2 + 1] + offa[hh * 32 + l * 8 + pp * 2 + 1] / slv;
        float px = gx * slv - 0.5f, py = gy * slv - 0.5f;
        float x0 = floorf(px), y0 = floorf(py);
        float fx = px - x0, fy = py - y0;
        int xi = (int)x0 + (tap & 1), yi = (int)y0 + (tap >> 1);
        float wtt = ((tap & 1) ? fx : (1.f - fx)) * ((tap >> 1) ? fy : (1.f - fy));
        int g = -1;
        if (xi >= 0 && xi < s && yi >= 0 && yi < s) {
            int col = slx[l] + xi;
            int row = slx[4 + l] + yi;
            g = img_starts[l] + row * wl + col;
            if (mask[g]) g = -1;  // masked rows zeroed (incl. bias)
        }
        sw[t] = a * wtt;
        sg[t] = g;
    }
    __syncthreads();
    // ---- first-occurrence dedupe (within 128-tap level segment) ----
    int fi = -1;
    if (t < 512) {
        int g = sg[t];
        if (g >= 0) {
            fi = t;
            int base = t & ~127;
            for (int jj = base; jj < t; jj++) if (sg[jj] == g) { fi = jj; break; }
        }
    }
    // ---- leader ranks via ballot prefix ----
    bool islead = (fi == t);
    unsigned long long bal = __ballot(islead);
    int lane = t & 63, wid = t >> 6;
    if ((t & 63) == 0) wtot[wid] = __popcll(bal);
    __syncthreads();
    int woff = 0, U = 0;
    #pragma unroll
    for (int w = 0; w < 8; w++) {
        int c = wtot[w];
        if (w < wid) woff += c;
        U += c;
    }
    if (islead) {
        int r = woff + __popcll(bal & ((1ULL << lane) - 1ULL));
        rk[t] = r;
        ulist[r] = sg[t];
    }
    __syncthreads();
    // ---- accumulate per-unique per-head weights ----
    if (fi >= 0) {
        int hh = (t >> 4) & 7;
        atomicAdd(&uw[rk[fi] * 8 + hh], sw[t]);
    }
    __syncthreads();
    // ---- main gather: each unique row read once; write aggregates directly ----
    {
        int ch = t & 255, q = t >> 8;
        float a0 = 0.f, a1 = 0.f;
        for (int u = 0; u < U; u++) {
            int g = ulist[u];
            float v = src[(size_t)g * 256 + ch];
            a0 += uw[u * 8 + 2 * q] * v;
            a1 += uw[u * 8 + 2 * q + 1] * v;
        }
        aggb[(size_t)n * 2048 + (2 * q) * 256 + ch] = a0;
        aggb[(size_t)n * 2048 + (2 * q + 1) * 256 + ch] = a1;
    }
    // csum partials (deterministic)
    if (t < 64) {
        int hh = t >> 3, p = t & 7;
        float s = 0.f;
        for (int u = p; u < U; u += 8) s += uw[u * 8 + hh];
        pcs[t] = s;
    }
    __syncthreads();
    if (t < 8) {
        float cs = pcs[t * 8 + 0] + pcs[t * 8 + 1] + pcs[t * 8 + 2] + pcs[t * 8 + 3]
                 + pcs[t * 8 + 4] + pcs[t * 8 + 5] + pcs[t * 8 + 6] + pcs[t * 8 + 7];
        csumb[n * 8 + t] = cs;
    }
}

// ---------------- S4: pool + valproj + oproj + norm1 + ffn1 + ffn2 + norm3 ----------------
// grid 128 (per edge), block 1024; ffn weights bf16-packed
__global__ __launch_bounds__(1024) void k_tail(const float* __restrict__ aggb,
                                               const float* __restrict__ csumb,
                                               const float* __restrict__ x1,
                                               const float* __restrict__ valwT,
                                               const float* __restrict__ valb,
                                               const float* __restrict__ ojwT,
                                               const float* __restrict__ ojb,
                                               const float* __restrict__ n1w,
                                               const float* __restrict__ n1b,
                                               const uint* __restrict__ Pl1,
                                               const float* __restrict__ l1b,
                                               const uint* __restrict__ Pl2,
                                               const float* __restrict__ l2b,
                                               const float* __restrict__ n3w,
                                               const float* __restrict__ n3b,
                                               float* __restrict__ out) {
    int e = blockIdx.x, t = threadIdx.x;
    __shared__ float pooledA[2048], csm[8], red[8], row[256], x2s[256], h1s[1024], part[1024];
    #pragma unroll
    for (int k = 0; k < 2; k++) {
        int i = k * 1024 + t;
        pooledA[i] = (aggb[(size_t)(3 * e) * 2048 + i] + aggb[(size_t)(3 * e + 1) * 2048 + i]
                    + aggb[(size_t)(3 * e + 2) * 2048 + i]) * (1.f / 3.f);
    }
    if (t < 8)
        csm[t] = (csumb[(3 * e) * 8 + t] + csumb[(3 * e + 1) * 8 + t] + csumb[(3 * e + 2) * 8 + t]) * (1.f / 3.f);
    __syncthreads();
    // ---- val projection of pooled aggregate (linearity: proj after pooling) ----
    {
        int o = t & 255, c = t >> 8, hh = o >> 5;
        const float* pa = pooledA + hh * 256 + c * 64;
        const float* w = valwT + (size_t)(c * 64) * 256 + o;
        float acc = 0.f;
        #pragma unroll 8
        for (int i = 0; i < 64; i++) acc += pa[i] * w[(size_t)i * 256];
        part[t] = acc;
    }
    __syncthreads();
    if (t < 256)
        row[t] = part[t] + part[256 + t] + part[512 + t] + part[768 + t] + csm[t >> 5] * valb[t];
    __syncthreads();
    // ---- oproj: 256 outputs x 4 chunks of 64 ----
    {
        int o = t & 255, c = t >> 8;
        float acc = 0.f;
        #pragma unroll 8
        for (int i = c * 64; i < c * 64 + 64; i++) acc += row[i] * ojwT[(size_t)i * 256 + o];
        part[t] = acc;
    }
    __syncthreads();
    // norm1
    {
        float acc = 0.f;
        if (t < 256) acc = part[t] + part[256 + t] + part[512 + t] + part[768 + t] + ojb[t] + x1[e * 256 + t];
        float mean = block_sum256f(acc, red) * (1.f / 256.f);
        float d0 = acc - mean;
        float var = block_sum256f((t < 256) ? d0 * d0 : 0.f, red) * (1.f / 256.f);
        if (t < 256) x2s[t] = d0 * rsqrtf(var + 1e-5f) * n1w[t] + n1b[t];
    }
    __syncthreads();
    // ffn1: one output per thread, packed K=256 (128 uints)
    {
        float acc = l1b[t];
        #pragma unroll 8
        for (int k2 = 0; k2 < 128; k2++) {
            uint u = Pl1[(size_t)k2 * 1024 + t];
            acc += x2s[2 * k2] * lo16(u);
            acc += x2s[2 * k2 + 1] * hi16(u);
        }
        h1s[t] = fmaxf(acc, 0.f);
    }
    __syncthreads();
    // ffn2: 256 outputs x 4 chunks of 128 packed
    {
        int o = t & 255, c = t >> 8;
        float acc = 0.f;
        #pragma unroll 8
        for (int k2 = c * 128; k2 < c * 128 + 128; k2++) {
            uint u = Pl2[(size_t)k2 * 256 + o];
            acc += h1s[2 * k2] * lo16(u);
            acc += h1s[2 * k2 + 1] * hi16(u);
        }
        part[t] = acc;
    }
    __syncthreads();
    // norm3 -> out
    {
        float acc = 0.f;
        if (t < 256) acc = part[t] + part[256 + t] + part[512 + t] + part[768 + t] + l2b[t] + x2s[t];
        float mean = block_sum256f(acc, red) * (1.f / 256.f);
        float d0 = acc - mean;
        float var = block_sum256f((t < 256) ? d0 * d0 : 0.f, red) * (1.f / 256.f);
        if (t < 256) out[e * 256 + t] = d0 * rsqrtf(var + 1e-5f) * n3w[t] + n3b[t];
    }
}

extern "C" void kernel_launch(void* const* d_in, const int* in_sizes, int n_in,
                              void* d_out, int out_size, void* d_ws, size_t ws_size,
                              hipStream_t stream) {
    (void)in_sizes; (void)n_in; (void)out_size; (void)ws_size;
    const float* tgt  = (const float*)d_in[0];
    const float* qpos = (const float*)d_in[1];
    const float* ec   = (const float*)d_in[2];
    const float* src  = (const float*)d_in[3];
    const unsigned char* mask = (const unsigned char*)d_in[4];
    const float* vr   = (const float*)d_in[5];
    const float* ipw  = (const float*)d_in[6];
    const float* ipb  = (const float*)d_in[7];
    const float* opw  = (const float*)d_in[8];
    const float* opb  = (const float*)d_in[9];
    const float* n1w  = (const float*)d_in[10];
    const float* n1b  = (const float*)d_in[11];
    const float* n2w  = (const float*)d_in[12];
    const float* n2b  = (const float*)d_in[13];
    const float* n3w  = (const float*)d_in[14];
    const float* n3b  = (const float*)d_in[15];
    const float* l0w  = (const float*)d_in[16];
    const float* l0b  = (const float*)d_in[17];
    const float* l1w  = (const float*)d_in[18];
    const float* l1b  = (const float*)d_in[19];
    const float* l2w  = (const float*)d_in[20];
    const float* l2b  = (const float*)d_in[21];
    const float* offw = (const float*)d_in[22];
    const float* offb = (const float*)d_in[23];
    const float* aww  = (const float*)d_in[24];
    const float* awb  = (const float*)d_in[25];
    const float* valw = (const float*)d_in[26];
    const float* valb = (const float*)d_in[27];
    const float* ojw  = (const float*)d_in[28];
    const float* ojb  = (const float*)d_in[29];

    float* ws     = (float*)d_ws;
    float* qkv    = ws;                    // 98304
    float* x1     = ws + 98304;            // 32768
    float* aggb   = ws + 131072;           // 786432 (384 x 2048)
    float* csumb  = ws + 917504;           // 3072
    float* opwT   = ws + 920576;           // 65536
    float* ojwT   = ws + 986112;           // 65536
    float* valwT  = ws + 1051648;          // 65536
    uint*  Pl1    = (uint*)(ws + 1117184); // 131072
    uint*  Pl2    = (uint*)(ws + 1248256); // 131072
    uint*  Pl0    = (uint*)(ws + 1379328); // 81920
    uint*  Poaw   = (uint*)(ws + 1461248); // 49152

    k_prep<<<1152, 256, 0, stream>>>(tgt, qpos, ipw, ipb, opw, ojw, valw, l1w, l2w,
                                     l0w, offw, aww,
                                     qkv, opwT, ojwT, valwT, Pl1, Pl2, Pl0, Poaw);
    k_edge<<<384, 1024, 0, stream>>>(qkv, tgt, qpos, opwT, opb, n2w, n2b, ec,
                                     Pl0, l0b, Poaw, offb, awb, vr, src, mask,
                                     x1, aggb, csumb);
    k_tail<<<128, 1024, 0, stream>>>(aggb, csumb, x1, valwT, valb,
                                     ojwT, ojb, n1w, n1b, Pl1, l1b, Pl2, l2b, n3w, n3b,
                                     (float*)d_out);
}